// Round 12
// baseline (136.620 us; speedup 1.0000x reference)
//
#include <hip/hip_runtime.h>

#define DM 1024
#define NH 16
#define DK 64
#define BB 2
#define SS 2048

typedef unsigned short u16;
typedef unsigned int   u32;
typedef __bf16 bf16x8 __attribute__((ext_vector_type(8)));
typedef float  f32x4  __attribute__((ext_vector_type(4)));
typedef float  f32x16 __attribute__((ext_vector_type(16)));

__device__ __forceinline__ u16 f2bf(float f){
  u32 u = __float_as_uint(f);
  u32 r = (u + 0x7FFFu + ((u >> 16) & 1u)) >> 16;   // RNE
  return (u16)r;
}
__device__ __forceinline__ float bf2f(u16 v){ return __uint_as_float(((u32)v) << 16); }

// packed bf16 convert: low16 = bf16(lo), high16 = bf16(hi), RNE
__device__ __forceinline__ u32 cvtpk(float lo, float hi){
  u32 r;
  asm volatile("v_cvt_pk_bf16_f32 %0, %1, %2" : "=v"(r) : "v"(lo), "v"(hi));
  return r;
}

__device__ __forceinline__ void gl16(const void* g, void* l){
  __builtin_amdgcn_global_load_lds((const __attribute__((address_space(1))) u32*)g,
                                   (__attribute__((address_space(3))) u32*)l, 16, 0, 0);
}
__device__ __forceinline__ f32x4 mfma16(bf16x8 a, bf16x8 b, f32x4 c){
  return __builtin_amdgcn_mfma_f32_16x16x32_bf16(a, b, c, 0, 0, 0);
}
__device__ __forceinline__ f32x16 mfma32(bf16x8 a, bf16x8 b, f32x16 c){
  return __builtin_amdgcn_mfma_f32_32x32x16_bf16(a, b, c, 0, 0, 0);
}

// ------- merged cast (x + 4 weights) + RoPE trig-table fill (tail blocks) -------
__global__ void k_cast(const float* __restrict__ x,  const float* __restrict__ wq,
                       const float* __restrict__ wk, const float* __restrict__ wv,
                       const float* __restrict__ wo, u16* __restrict__ xb,
                       u16* __restrict__ wb, float* __restrict__ tab){
  if (blockIdx.x >= 8192){
    int e = (blockIdx.x - 8192)*256 + threadIdx.x;   // [0, 65536)
    int p = e >> 5, j = e & 31;
    float s, c;
    sincosf((float)p * exp2f(-0.4152410118609203f * (float)j), &s, &c);
    float2 v; v.x = c; v.y = s;
    *(float2*)(tab + e*2) = v;
    return;
  }
  int e = blockIdx.x*1024 + threadIdx.x*4;
  int r = e >> 20;
  const float* s; u16* d; int local;
  if (r < 4){ s = x; d = xb; local = e; }
  else {
    const float* ws[4] = {wq, wk, wv, wo};
    int w = r - 4;
    local = e & 0xFFFFF;
    s = ws[w]; d = wb + ((size_t)w << 20);
  }
  float4 v = *(const float4*)(s + local);
  uint2 t; t.x = cvtpk(v.x, v.y); t.y = cvtpk(v.z, v.w);
  *(uint2*)(d + local) = t;
}

// ---------------- GEMM core R10 (verified): BK=32, triple-buffer, counted vmcnt ----
template<bool SWAP>
__device__ __forceinline__ void gemm_core(const u16* __restrict__ A, const u16* __restrict__ Bw,
                                          u16* S, f32x4 (&acc)[4][4]){
  const int tid = threadIdx.x, lane = tid & 63, wid = tid >> 6;
  const int m0 = blockIdx.y * 128, n0 = blockIdx.x * 128;
  const int wm = (wid >> 1) * 64, wn = (wid & 1) * 64;
  const int ql = lane & 15, lg = lane >> 4;

  #define STAGE_G(buf, k0)                                                       \
    _Pragma("unroll")                                                            \
    for (int i = 0; i < 4; i++){                                                 \
      int L = i*4096 + tid*16;                                                   \
      int r_ = L >> 7;                                                           \
      int orig = ((L >> 4) & 7) ^ (r_ & 7);                                      \
      const u16* src = (orig < 4)                                                \
          ? (A  + (size_t)(m0 + r_)*DM + (k0) + orig*8)                          \
          : (Bw + (size_t)(n0 + r_)*DM + (k0) + (orig - 4)*8);                   \
      gl16(src, (char*)(buf) + L);                                               \
    }

  #define COMPUTE_T(buf)                                                         \
    {                                                                            \
      bf16x8 af[4], bfr[4];                                                      \
      _Pragma("unroll")                                                          \
      for (int mi = 0; mi < 4; mi++){                                            \
        int r = wm + mi*16 + ql;                                                 \
        af[mi] = *(const bf16x8*)((char*)(buf) + r*128 + ((lg*16) ^ ((r & 7) << 4))); \
      }                                                                          \
      _Pragma("unroll")                                                          \
      for (int ni = 0; ni < 4; ni++){                                            \
        int r = wn + ni*16 + ql;                                                 \
        bfr[ni] = *(const bf16x8*)((char*)(buf) + r*128 + ((64 + lg*16) ^ ((r & 7) << 4))); \
      }                                                                          \
      __builtin_amdgcn_s_setprio(1);                                             \
      _Pragma("unroll")                                                          \
      for (int mi = 0; mi < 4; mi++)                                             \
        _Pragma("unroll")                                                        \
        for (int ni = 0; ni < 4; ni++)                                           \
          acc[mi][ni] = SWAP ? mfma16(bfr[ni], af[mi], acc[mi][ni])              \
                             : mfma16(af[mi], bfr[ni], acc[mi][ni]);             \
      __builtin_amdgcn_s_setprio(0);                                             \
    }

  char* b0 = (char*)S;
  char* b1 = (char*)S + 16384;
  char* b2 = (char*)S + 32768;

  STAGE_G(b0, 0);
  STAGE_G(b1, 32);

  #pragma unroll 3
  for (int t = 0; t < 30; t++){
    asm volatile("s_waitcnt vmcnt(4)" ::: "memory");   // stage(t) done, stage(t+1) in flight
    __builtin_amdgcn_s_barrier();                      // everyone's stage(t) done
    STAGE_G(b2, (t+2)*32);                             // depth-2 prefetch
    COMPUTE_T(b0);
    char* tmp = b0; b0 = b1; b1 = b2; b2 = tmp;        // rotate (static after unroll 3)
  }
  asm volatile("s_waitcnt vmcnt(4)" ::: "memory");
  __builtin_amdgcn_s_barrier();
  COMPUTE_T(b0);
  { char* tmp = b0; b0 = b1; b1 = b2; b2 = tmp; }
  asm volatile("s_waitcnt vmcnt(0)" ::: "memory");
  __builtin_amdgcn_s_barrier();
  COMPUTE_T(b0);

  #undef STAGE_G
  #undef COMPUTE_T
}

// QKV GEMM. z=0/1: fused RoPE (trig table), row-major out. z=2: V written
// TRANSPOSED as V^T[b][h*64+d][s]  (feature-major, so attn can gl16-stage it).
__global__ __launch_bounds__(256) void k_gemm_qkv(const u16* __restrict__ xb, const u16* __restrict__ Wb,
                                                  u16* __restrict__ Qb, u16* __restrict__ Kb,
                                                  u16* __restrict__ Vt_g, const int* __restrict__ pos,
                                                  const float* __restrict__ tab){
  __shared__ __align__(16) u16 S[3*8192];
  const int z = blockIdx.z;
  const u16* Bw = Wb + ((size_t)z << 20);
  f32x4 acc[4][4] = {};
  gemm_core<true>(xb, Bw, S, acc);
  const int lane = threadIdx.x & 63, wid = threadIdx.x >> 6;
  const int m0 = blockIdx.y*128 + (wid >> 1)*64, n0 = blockIdx.x*128 + (wid & 1)*64;
  const int ql = lane & 15, lg = lane >> 4;

  if (z == 2){
    #pragma unroll
    for (int mi = 0; mi < 4; mi++){
      const int mrow = m0 + mi*16 + ql;
      const int bq = mrow >> 11, sq = mrow & (SS-1);
      u16* vt = Vt_g + ((size_t)bq*NH*DK)*SS + sq;
      #pragma unroll
      for (int ni = 0; ni < 4; ni++){
        const int nb = n0 + ni*16 + lg*4;
        #pragma unroll
        for (int r = 0; r < 4; r++)
          vt[(size_t)(nb + r)*SS] = f2bf(acc[mi][ni][r]);
      }
    }
    return;
  }

  u16* C = (z == 0) ? Qb : Kb;
  const float4* tab4 = (const float4*)tab;     // [p][j/2] = {cos j, sin j, cos j+1, sin j+1}
  #pragma unroll
  for (int mi = 0; mi < 4; mi++){
    const int mrow = m0 + mi*16 + ql;
    const int p = pos[mrow & (SS-1)];
    #pragma unroll
    for (int ni = 0; ni < 4; ni++){
      const int nb = n0 + ni*16 + lg*4;        // 4 consecutive n, multiple of 4
      float o0 = acc[mi][ni][0], o1 = acc[mi][ni][1];
      float o2 = acc[mi][ni][2], o3 = acc[mi][ni][3];
      int j0 = (nb >> 1) & 31;                 // even pair index within head
      float4 cs = tab4[p*16 + (j0 >> 1)];
      float t0 = o0*cs.x - o1*cs.y, t1 = o0*cs.y + o1*cs.x;
      o0 = t0; o1 = t1;
      t0 = o2*cs.z - o3*cs.w; t1 = o2*cs.w + o3*cs.z;
      o2 = t0; o3 = t1;
      uint2 w; w.x = cvtpk(o0, o1); w.y = cvtpk(o2, o3);
      *(uint2*)(C + (size_t)mrow*DM + nb) = w;
    }
  }
}

__global__ __launch_bounds__(256) void k_gemm_out(const u16* __restrict__ AO, const u16* __restrict__ Wo,
                                                  float* __restrict__ Co){
  __shared__ __align__(16) u16 S[3*8192];
  f32x4 acc[4][4] = {};
  gemm_core<false>(AO, Wo, S, acc);
  const int lane = threadIdx.x & 63, wid = threadIdx.x >> 6;
  const int m0 = blockIdx.y*128 + (wid >> 1)*64, n0 = blockIdx.x*128 + (wid & 1)*64;
  #pragma unroll
  for (int mi = 0; mi < 4; mi++)
    #pragma unroll
    for (int ni = 0; ni < 4; ni++)
      #pragma unroll
      for (int r = 0; r < 4; r++){
        int m = m0 + mi*16 + (lane >> 4)*4 + r;
        int n = n0 + ni*16 + (lane & 15);
        Co[(size_t)m*DM + n] = acc[mi][ni][r];
      }
}

// ---------------- flash attention, causal — R12: 32x32 MFMA, 4 waves x 32 q ------
// Swapped QK^T via mfma_32x32x16: C col = lane&31 = q -> softmax is in-lane over 32
// scores + ONE shfl_xor(32). Per-q LDS reads drop ~45% (frags feed 32 q, not 16).
// C/D layout (m74/m101): row = (r&3)+8*(r>>2)+4*(lane>>5), col = lane&31.
// A/B frag: row = lane&31, k = (lane>>5)*8+j. P via per-wave swizzled LDS as before.
__global__ __launch_bounds__(256) void k_attn(const u16* __restrict__ Q, const u16* __restrict__ K,
                                              const u16* __restrict__ Vt_g, u16* __restrict__ AO){
  __shared__ __align__(16) u16 Ks[3][64*64];
  __shared__ __align__(16) u16 Vt[3][64*64];
  __shared__ __align__(16) u16 Ps[4][32*64];
  const int tid = threadIdx.x, lane = tid & 63, wid = tid >> 6;
  const int b = blockIdx.z, h = blockIdx.y;
  const int qb = b ? (15 - (int)blockIdx.x) : (int)blockIdx.x;   // balanced pairing
  const int qw = qb*128 + wid*32;                                 // wave's 32 q rows
  const size_t base = ((size_t)b*SS)*DM + (size_t)h*DK;
  const size_t vtb  = ((size_t)b*NH + h)*DK*SS;                   // V^T base
  const int qi = lane & 31, hh = lane >> 5;
  const int NT = 2*qb + 2;

  // Q frags: 4 chunks of K=16; lane: row q = qi, k = 16*kk + hh*8 + j
  const u16* qptr = Q + base + (size_t)(qw + qi)*DM + hh*8;
  bf16x8 qf0 = *(const bf16x8*)(qptr);
  bf16x8 qf1 = *(const bf16x8*)(qptr + 16);
  bf16x8 qf2 = *(const bf16x8*)(qptr + 32);
  bf16x8 qf3 = *(const bf16x8*)(qptr + 48);

  f32x16 oacc0 = {}, oacc1 = {};
  float m = -3e38f, lsum = 0.f;
  const float SC = 0.18033688011112042f;        // (1/sqrt(64)) * log2(e)
  const float THR = 8.0f / SC;

  // staging: 2 gl16 per tensor per thread (8KB tile / 256 thr / 16B)
  #define STAGE_A(bi, t)                                                          \
    {                                                                             \
      const int kn0_ = (t)*64;                                                    \
      _Pragma("unroll")                                                           \
      for (int i_ = 0; i_ < 2; i_++){                                             \
        int L = i_*4096 + tid*16;                                                 \
        int row_ = L >> 7;                                                        \
        int inner = (L & 127) ^ ((row_ & 7) << 4);                                \
        gl16(K    + base + (size_t)(kn0_ + row_)*DM + (inner >> 1), (char*)Ks[bi] + L); \
        gl16(Vt_g + vtb  + (size_t)row_*SS + kn0_ + (inner >> 1), (char*)Vt[bi] + L);   \
      }                                                                           \
    }

  STAGE_A(0, 0);
  STAGE_A(1, 1);                      // NT >= 2 always
  asm volatile("s_waitcnt vmcnt(4)" ::: "memory");   // Q + stage(0) done
  __builtin_amdgcn_s_barrier();

  int c0 = 0, c1 = 1, c2 = 2;
  for (int kt = 0; kt < NT; kt++){
    const int kv0 = kt*64;
    const bool have2 = (kt + 2 < NT);
    if (have2) STAGE_A(c2, kt + 2);   // depth-2 prefetch

    const bool active = (kv0 <= qw + 31);
    if (active){
      f32x16 sf0 = {}, sf1 = {};
      __builtin_amdgcn_s_setprio(1);
      #define QKSTEP(KK, QF)                                                      \
        {                                                                         \
          const int co = (KK)*32 + hh*16;                                         \
          int ra = qi, rb = 32 + qi;                                              \
          bf16x8 kfa = *(const bf16x8*)((const char*)Ks[c0] + ((ra*128 + co) ^ ((ra & 7) << 4))); \
          bf16x8 kfb = *(const bf16x8*)((const char*)Ks[c0] + ((rb*128 + co) ^ ((rb & 7) << 4))); \
          sf0 = mfma32(kfa, QF, sf0);                                             \
          sf1 = mfma32(kfb, QF, sf1);                                             \
        }
      QKSTEP(0, qf0) QKSTEP(1, qf1) QKSTEP(2, qf2) QKSTEP(3, qf3)
      #undef QKSTEP
      __builtin_amdgcn_s_setprio(0);

      if (kv0 + 63 > qw){                       // mask (diagonal overlap)
        const int qa = qw + qi;
        #pragma unroll
        for (int r = 0; r < 16; r++){
          int rowoff = (r & 3) + 8*(r >> 2) + 4*hh;
          sf0[r] = (kv0 + rowoff      <= qa) ? sf0[r] : -3e38f;
          sf1[r] = (kv0 + 32 + rowoff <= qa) ? sf1[r] : -3e38f;
        }
      }

      float mx = -3e38f;
      #pragma unroll
      for (int r = 0; r < 16; r++) mx = fmaxf(mx, fmaxf(sf0[r], sf1[r]));

      if (!__all(mx <= m + THR)){               // defer-max
        mx = fmaxf(mx, __shfl_xor(mx, 32));
        const float mn = fmaxf(m, mx);
        const float alpha = exp2f((m - mn)*SC);
        oacc0 *= alpha;
        oacc1 *= alpha;
        lsum *= alpha;
        m = mn;
      }

      const float nms = -m*SC;
      float p0[16], p1[16];
      float psum = 0.f;
      #pragma unroll
      for (int r = 0; r < 16; r++){
        p0[r] = exp2f(fmaf(sf0[r], SC, nms));
        p1[r] = exp2f(fmaf(sf1[r], SC, nms));
        psum += p0[r] + p1[r];
      }
      lsum += psum;

      // P -> LDS: u32 pairs; reg pair (2w,2w+1) -> kv pair base pb = (w&1)*2+(w>>1)*8
      #pragma unroll
      for (int w = 0; w < 8; w++){
        const int pb = (w & 1)*2 + (w >> 1)*8;
        const int kvb0 = 4*hh + pb;
        const int kvb1 = 32 + 4*hh + pb;
        *(u32*)((char*)Ps[wid] + ((qi*128 + kvb0*2) ^ ((qi & 7) << 4))) = cvtpk(p0[2*w], p0[2*w+1]);
        *(u32*)((char*)Ps[wid] + ((qi*128 + kvb1*2) ^ ((qi & 7) << 4))) = cvtpk(p1[2*w], p1[2*w+1]);
      }

      // PV: oacc[fd] += V[d=32fd+..][kv] * P[q][kv], k chunks kc of 16 kv
      __builtin_amdgcn_s_setprio(1);
      #pragma unroll
      for (int kc = 0; kc < 4; kc++){
        const int co = kc*32 + hh*16;
        bf16x8 pf = *(const bf16x8*)((const char*)Ps[wid] + ((qi*128 + co) ^ ((qi & 7) << 4)));
        int da = qi, db = 32 + qi;
        bf16x8 vfa = *(const bf16x8*)((const char*)Vt[c0] + ((da*128 + co) ^ ((da & 7) << 4)));
        bf16x8 vfb = *(const bf16x8*)((const char*)Vt[c0] + ((db*128 + co) ^ ((db & 7) << 4)));
        oacc0 = mfma32(vfa, pf, oacc0);
        oacc1 = mfma32(vfb, pf, oacc1);
      }
      __builtin_amdgcn_s_setprio(0);
    }

    if (kt + 1 < NT){
      if (have2) asm volatile("s_waitcnt vmcnt(4)" ::: "memory");  // stage(t+1) done
      else       asm volatile("s_waitcnt vmcnt(0)" ::: "memory");  // final drain
      __builtin_amdgcn_s_barrier();
    }
    int tmp = c0; c0 = c1; c1 = c2; c2 = tmp;
  }
  #undef STAGE_A

  // epilogue: lsum across the q-row's two lanes; O -> per-wave LDS -> coalesced
  lsum += __shfl_xor(lsum, 32);
  const float rl = 1.0f / lsum;
  #pragma unroll
  for (int w = 0; w < 8; w++){
    const int pb = (w & 1)*2 + (w >> 1)*8;
    const int db0 = 4*hh + pb;
    const int db1 = 32 + 4*hh + pb;
    *(u32*)((char*)Ps[wid] + ((qi*128 + db0*2) ^ ((qi & 7) << 4))) =
        cvtpk(oacc0[2*w]*rl, oacc0[2*w+1]*rl);
    *(u32*)((char*)Ps[wid] + ((qi*128 + db1*2) ^ ((qi & 7) << 4))) =
        cvtpk(oacc1[2*w]*rl, oacc1[2*w+1]*rl);
  }
  #pragma unroll
  for (int pass = 0; pass < 4; pass++){
    int qr = pass*8 + (lane >> 3);
    int d0 = (lane & 7)*8;
    bf16x8 row = *(const bf16x8*)((const char*)Ps[wid] + ((qr*128 + d0*2) ^ ((qr & 7) << 4)));
    *(bf16x8*)(AO + base + (size_t)(qw + qr)*DM + d0) = row;
  }
}

// ---------------- launch ----------------
extern "C" void kernel_launch(void* const* d_in, const int* in_sizes, int n_in,
                              void* d_out, int out_size, void* d_ws, size_t ws_size,
                              hipStream_t stream){
  const float* x   = (const float*)d_in[0];
  const float* Wq  = (const float*)d_in[1];
  const float* Wk  = (const float*)d_in[2];
  const float* Wv  = (const float*)d_in[3];
  const float* Wo  = (const float*)d_in[4];
  const int*   pos = (const int*)d_in[5];
  float* out = (float*)d_out;

  const size_t NEED = ((size_t)41 << 20);   // 40 MiB buffers + 512 KiB trig table
  if (ws_size < NEED){
    hipMemsetAsync(d_out, 0x7f, (size_t)out_size * sizeof(float), stream);
    return;
  }

  char* ws = (char*)d_ws;
  u16* xb   = (u16*)(ws);
  u16* Wb   = (u16*)(ws + ((size_t)8  << 20));
  u16* Qb   = (u16*)(ws + ((size_t)16 << 20));
  u16* Kb   = (u16*)(ws + ((size_t)24 << 20));
  u16* Vt   = (u16*)(ws + ((size_t)32 << 20));   // V^T [b][h*64+d][s]
  float* tab = (float*)(ws + ((size_t)40 << 20));
  u16* AO = xb;

  k_cast<<<8448, 256, 0, stream>>>(x, Wq, Wk, Wv, Wo, xb, Wb, tab);
  k_gemm_qkv<<<dim3(8, 32, 3), 256, 0, stream>>>(xb, Wb, Qb, Kb, Vt, pos, tab);
  k_attn<<<dim3(16, 16, 2), 256, 0, stream>>>(Qb, Kb, Vt, AO);
  k_gemm_out<<<dim3(8, 32), 256, 0, stream>>>(AO, Wb + ((size_t)3 << 20), out);
}

// Round 13
// 118.237 us; speedup vs baseline: 1.1555x; 1.1555x over previous
//
#include <hip/hip_runtime.h>

#define DM 1024
#define NH 16
#define DK 64
#define BB 2
#define SS 2048

typedef unsigned short u16;
typedef unsigned int   u32;
typedef __bf16 bf16x8 __attribute__((ext_vector_type(8)));
typedef float  f32x4  __attribute__((ext_vector_type(4)));

__device__ __forceinline__ u16 f2bf(float f){
  u32 u = __float_as_uint(f);
  u32 r = (u + 0x7FFFu + ((u >> 16) & 1u)) >> 16;   // RNE
  return (u16)r;
}
__device__ __forceinline__ float bf2f(u16 v){ return __uint_as_float(((u32)v) << 16); }

// packed bf16 convert: low16 = bf16(lo), high16 = bf16(hi), RNE
__device__ __forceinline__ u32 cvtpk(float lo, float hi){
  u32 r;
  asm volatile("v_cvt_pk_bf16_f32 %0, %1, %2" : "=v"(r) : "v"(lo), "v"(hi));
  return r;
}

__device__ __forceinline__ void gl16(const void* g, void* l){
  __builtin_amdgcn_global_load_lds((const __attribute__((address_space(1))) u32*)g,
                                   (__attribute__((address_space(3))) u32*)l, 16, 0, 0);
}
__device__ __forceinline__ f32x4 mfma16(bf16x8 a, bf16x8 b, f32x4 c){
  return __builtin_amdgcn_mfma_f32_16x16x32_bf16(a, b, c, 0, 0, 0);
}

// ------- merged cast (x + 4 weights) + RoPE trig-table fill (tail blocks) -------
__global__ void k_cast(const float* __restrict__ x,  const float* __restrict__ wq,
                       const float* __restrict__ wk, const float* __restrict__ wv,
                       const float* __restrict__ wo, u16* __restrict__ xb,
                       u16* __restrict__ wb, float* __restrict__ tab){
  if (blockIdx.x >= 8192){
    int e = (blockIdx.x - 8192)*256 + threadIdx.x;   // [0, 65536)
    int p = e >> 5, j = e & 31;
    float s, c;
    sincosf((float)p * exp2f(-0.4152410118609203f * (float)j), &s, &c);
    float2 v; v.x = c; v.y = s;
    *(float2*)(tab + e*2) = v;
    return;
  }
  int e = blockIdx.x*1024 + threadIdx.x*4;
  int r = e >> 20;
  const float* s; u16* d; int local;
  if (r < 4){ s = x; d = xb; local = e; }
  else {
    const float* ws[4] = {wq, wk, wv, wo};
    int w = r - 4;
    local = e & 0xFFFFF;
    s = ws[w]; d = wb + ((size_t)w << 20);
  }
  float4 v = *(const float4*)(s + local);
  uint2 t; t.x = cvtpk(v.x, v.y); t.y = cvtpk(v.z, v.w);
  *(uint2*)(d + local) = t;
}

// XCD-chunked bijective block swizzle (nwg % 8 == 0): hw round-robins linear id
// over 8 XCDs; remap so each XCD owns a CONTIGUOUS chunk -> same-y blocks (sharing
// the A panel) land on one XCD's L2 (T1; FETCH-evidence: 70.7MB vs 14MB ideal).
__device__ __forceinline__ int xcd_swz(int lin, int nwg){
  return (lin & 7) * (nwg >> 3) + (lin >> 3);
}

// ---------------- GEMM core R10 (verified): BK=32, triple-buffer, counted vmcnt ----
template<bool SWAP>
__device__ __forceinline__ void gemm_core(const u16* __restrict__ A, const u16* __restrict__ Bw,
                                          u16* S, f32x4 (&acc)[4][4], int m0, int n0){
  const int tid = threadIdx.x, lane = tid & 63, wid = tid >> 6;
  const int wm = (wid >> 1) * 64, wn = (wid & 1) * 64;
  const int ql = lane & 15, lg = lane >> 4;

  #define STAGE_G(buf, k0)                                                       \
    _Pragma("unroll")                                                            \
    for (int i = 0; i < 4; i++){                                                 \
      int L = i*4096 + tid*16;                                                   \
      int r_ = L >> 7;                                                           \
      int orig = ((L >> 4) & 7) ^ (r_ & 7);                                      \
      const u16* src = (orig < 4)                                                \
          ? (A  + (size_t)(m0 + r_)*DM + (k0) + orig*8)                          \
          : (Bw + (size_t)(n0 + r_)*DM + (k0) + (orig - 4)*8);                   \
      gl16(src, (char*)(buf) + L);                                               \
    }

  #define COMPUTE_T(buf)                                                         \
    {                                                                            \
      bf16x8 af[4], bfr[4];                                                      \
      _Pragma("unroll")                                                          \
      for (int mi = 0; mi < 4; mi++){                                            \
        int r = wm + mi*16 + ql;                                                 \
        af[mi] = *(const bf16x8*)((char*)(buf) + r*128 + ((lg*16) ^ ((r & 7) << 4))); \
      }                                                                          \
      _Pragma("unroll")                                                          \
      for (int ni = 0; ni < 4; ni++){                                            \
        int r = wn + ni*16 + ql;                                                 \
        bfr[ni] = *(const bf16x8*)((char*)(buf) + r*128 + ((64 + lg*16) ^ ((r & 7) << 4))); \
      }                                                                          \
      __builtin_amdgcn_s_setprio(1);                                             \
      _Pragma("unroll")                                                          \
      for (int mi = 0; mi < 4; mi++)                                             \
        _Pragma("unroll")                                                        \
        for (int ni = 0; ni < 4; ni++)                                           \
          acc[mi][ni] = SWAP ? mfma16(bfr[ni], af[mi], acc[mi][ni])              \
                             : mfma16(af[mi], bfr[ni], acc[mi][ni]);             \
      __builtin_amdgcn_s_setprio(0);                                             \
    }

  char* b0 = (char*)S;
  char* b1 = (char*)S + 16384;
  char* b2 = (char*)S + 32768;

  STAGE_G(b0, 0);
  STAGE_G(b1, 32);

  #pragma unroll 3
  for (int t = 0; t < 30; t++){
    asm volatile("s_waitcnt vmcnt(4)" ::: "memory");   // stage(t) done, stage(t+1) in flight
    __builtin_amdgcn_s_barrier();                      // everyone's stage(t) done
    STAGE_G(b2, (t+2)*32);                             // depth-2 prefetch
    COMPUTE_T(b0);
    char* tmp = b0; b0 = b1; b1 = b2; b2 = tmp;        // rotate (static after unroll 3)
  }
  asm volatile("s_waitcnt vmcnt(4)" ::: "memory");
  __builtin_amdgcn_s_barrier();
  COMPUTE_T(b0);
  { char* tmp = b0; b0 = b1; b1 = b2; b2 = tmp; }
  asm volatile("s_waitcnt vmcnt(0)" ::: "memory");
  __builtin_amdgcn_s_barrier();
  COMPUTE_T(b0);

  #undef STAGE_G
  #undef COMPUTE_T
}

// QKV GEMM. z=0/1: fused RoPE (trig table), row-major out. z=2: V written
// TRANSPOSED as V^T[b][h*64+d][s]  (feature-major, so attn can gl16-stage it).
__global__ __launch_bounds__(256) void k_gemm_qkv(const u16* __restrict__ xb, const u16* __restrict__ Wb,
                                                  u16* __restrict__ Qb, u16* __restrict__ Kb,
                                                  u16* __restrict__ Vt_g, const int* __restrict__ pos,
                                                  const float* __restrict__ tab){
  __shared__ __align__(16) u16 S[3*8192];
  // XCD swizzle over the 768-block grid (8 x, 32 y, 3 z)
  int lin = (int)blockIdx.x + 8*((int)blockIdx.y + 32*(int)blockIdx.z);
  lin = xcd_swz(lin, 768);
  const int bx = lin & 7, by = (lin >> 3) & 31, z = lin >> 8;
  const int m0 = by * 128, n0 = bx * 128;

  const u16* Bw = Wb + ((size_t)z << 20);
  f32x4 acc[4][4] = {};
  gemm_core<true>(xb, Bw, S, acc, m0, n0);
  const int lane = threadIdx.x & 63, wid = threadIdx.x >> 6;
  const int wm0 = m0 + (wid >> 1)*64, wn0 = n0 + (wid & 1)*64;
  const int ql = lane & 15, lg = lane >> 4;

  if (z == 2){
    #pragma unroll
    for (int mi = 0; mi < 4; mi++){
      const int mrow = wm0 + mi*16 + ql;
      const int bq = mrow >> 11, sq = mrow & (SS-1);
      u16* vt = Vt_g + ((size_t)bq*NH*DK)*SS + sq;
      #pragma unroll
      for (int ni = 0; ni < 4; ni++){
        const int nb = wn0 + ni*16 + lg*4;
        #pragma unroll
        for (int r = 0; r < 4; r++)
          vt[(size_t)(nb + r)*SS] = f2bf(acc[mi][ni][r]);
      }
    }
    return;
  }

  u16* C = (z == 0) ? Qb : Kb;
  const float4* tab4 = (const float4*)tab;     // [p][j/2] = {cos j, sin j, cos j+1, sin j+1}
  #pragma unroll
  for (int mi = 0; mi < 4; mi++){
    const int mrow = wm0 + mi*16 + ql;
    const int p = pos[mrow & (SS-1)];
    #pragma unroll
    for (int ni = 0; ni < 4; ni++){
      const int nb = wn0 + ni*16 + lg*4;       // 4 consecutive n, multiple of 4
      float o0 = acc[mi][ni][0], o1 = acc[mi][ni][1];
      float o2 = acc[mi][ni][2], o3 = acc[mi][ni][3];
      int j0 = (nb >> 1) & 31;                 // even pair index within head
      float4 cs = tab4[p*16 + (j0 >> 1)];
      float t0 = o0*cs.x - o1*cs.y, t1 = o0*cs.y + o1*cs.x;
      o0 = t0; o1 = t1;
      t0 = o2*cs.z - o3*cs.w; t1 = o2*cs.w + o3*cs.z;
      o2 = t0; o3 = t1;
      uint2 w; w.x = cvtpk(o0, o1); w.y = cvtpk(o2, o3);
      *(uint2*)(C + (size_t)mrow*DM + nb) = w;
    }
  }
}

__global__ __launch_bounds__(256) void k_gemm_out(const u16* __restrict__ AO, const u16* __restrict__ Wo,
                                                  float* __restrict__ Co){
  __shared__ __align__(16) u16 S[3*8192];
  int lin = (int)blockIdx.x + 8*(int)blockIdx.y;
  lin = xcd_swz(lin, 256);
  const int bx = lin & 7, by = lin >> 3;
  const int m0 = by * 128, n0 = bx * 128;

  f32x4 acc[4][4] = {};
  gemm_core<false>(AO, Wo, S, acc, m0, n0);
  const int lane = threadIdx.x & 63, wid = threadIdx.x >> 6;
  const int wm0 = m0 + (wid >> 1)*64, wn0 = n0 + (wid & 1)*64;
  #pragma unroll
  for (int mi = 0; mi < 4; mi++)
    #pragma unroll
    for (int ni = 0; ni < 4; ni++)
      #pragma unroll
      for (int r = 0; r < 4; r++){
        int m = wm0 + mi*16 + (lane >> 4)*4 + r;
        int n = wn0 + ni*16 + (lane & 15);
        Co[(size_t)m*DM + n] = acc[mi][ni][r];
      }
}

// ---------------- flash attention, causal, 8-wave QBLK=128 (R11, verified 58us) ----
__global__ __launch_bounds__(512) void k_attn(const u16* __restrict__ Q, const u16* __restrict__ K,
                                              const u16* __restrict__ Vt_g, u16* __restrict__ AO){
  __shared__ __align__(16) u16 Ks[3][64*64];
  __shared__ __align__(16) u16 Vt[3][64*64];
  __shared__ __align__(16) u16 Ps[8][16*64];
  const int tid = threadIdx.x, lane = tid & 63, wid = tid >> 6;
  const int b = blockIdx.z, h = blockIdx.y;
  const int qb = b ? (15 - (int)blockIdx.x) : (int)blockIdx.x;   // balanced pairing
  const int qw = qb*128 + wid*16;
  const size_t base = ((size_t)b*SS)*DM + (size_t)h*DK;
  const size_t vtb  = ((size_t)b*NH + h)*DK*SS;                  // V^T base
  const int ql = lane & 15, lg = lane >> 4;
  const int NT = 2*qb + 2;

  const u16* qptr = Q + base + (size_t)(qw + ql)*DM + lg*8;
  bf16x8 qf0 = *(const bf16x8*)(qptr);
  bf16x8 qf1 = *(const bf16x8*)(qptr + 32);

  f32x4 oacc[4] = {};
  float m = -3e38f, lsum = 0.f;
  const float SC = 0.18033688011112042f;        // (1/sqrt(64)) * log2(e)
  const float THR = 8.0f / SC;

  const int srow = tid >> 3;
  const int sin = ((tid & 7) * 16) ^ ((srow & 7) << 4);   // pre-swizzled byte col

  #define STAGE_A(bi, t)                                                          \
    {                                                                             \
      const int kn0_ = (t)*64;                                                    \
      gl16(K    + base + (size_t)(kn0_ + srow)*DM + (sin >> 1), (char*)Ks[bi] + tid*16); \
      gl16(Vt_g + vtb  + (size_t)srow*SS + kn0_ + (sin >> 1), (char*)Vt[bi] + tid*16);   \
    }

  STAGE_A(0, 0);
  STAGE_A(1, 1);                      // NT >= 2 always
  asm volatile("s_waitcnt vmcnt(2)" ::: "memory");   // stage(0) (and Q) done
  __builtin_amdgcn_s_barrier();

  int c0 = 0, c1 = 1, c2 = 2;
  for (int kt = 0; kt < NT; kt++){
    const int kv0 = kt*64;
    const bool have2 = (kt + 2 < NT);
    if (have2) STAGE_A(c2, kt + 2);   // depth-2 prefetch

    const bool active = (kv0 <= qw + 15);
    if (active){
      f32x4 sf[4] = {};
      __builtin_amdgcn_s_setprio(1);
      #pragma unroll
      for (int kk = 0; kk < 2; kk++){
        const int co = kk*64 + lg*16;
        #pragma unroll
        for (int f = 0; f < 4; f++){
          int kvr = f*16 + ql;
          bf16x8 kf = *(const bf16x8*)((const char*)Ks[c0] + ((kvr*128 + co) ^ ((kvr & 7) << 4)));
          sf[f] = mfma16(kf, kk ? qf1 : qf0, sf[f]);
        }
      }
      __builtin_amdgcn_s_setprio(0);

      if (kv0 + 63 > qw){
        const int qa = qw + ql;
        #pragma unroll
        for (int f = 0; f < 4; f++)
          #pragma unroll
          for (int r = 0; r < 4; r++){
            int kva = kv0 + f*16 + lg*4 + r;
            sf[f][r] = (kva <= qa) ? sf[f][r] : -3e38f;
          }
      }

      float mx01 = fmaxf(fmaxf(sf[0][0], sf[0][1]), fmaxf(sf[0][2], sf[0][3]));
      float mx23 = fmaxf(fmaxf(sf[1][0], sf[1][1]), fmaxf(sf[1][2], sf[1][3]));
      float mx45 = fmaxf(fmaxf(sf[2][0], sf[2][1]), fmaxf(sf[2][2], sf[2][3]));
      float mx67 = fmaxf(fmaxf(sf[3][0], sf[3][1]), fmaxf(sf[3][2], sf[3][3]));
      float mx = fmaxf(fmaxf(mx01, mx23), fmaxf(mx45, mx67));

      if (!__all(mx <= m + THR)){               // defer-max
        mx = fmaxf(mx, __shfl_xor(mx, 16));
        mx = fmaxf(mx, __shfl_xor(mx, 32));
        const float mn = fmaxf(m, mx);
        const float alpha = exp2f((m - mn)*SC);
        #pragma unroll
        for (int ni = 0; ni < 4; ni++) oacc[ni] *= alpha;
        lsum *= alpha;
        m = mn;
      }

      const float nms = -m*SC;
      float p[4][4];
      float psum = 0.f;
      #pragma unroll
      for (int f = 0; f < 4; f++)
        #pragma unroll
        for (int r = 0; r < 4; r++){
          p[f][r] = exp2f(fmaf(sf[f][r], SC, nms));
          psum += p[f][r];
        }
      lsum += psum;

      #pragma unroll
      for (int f = 0; f < 4; f++)
        #pragma unroll
        for (int r = 0; r < 4; r += 2){
          int kv = f*16 + lg*4 + r;
          int byteoff = (ql*128 + kv*2) ^ ((ql & 7) << 4);
          *(u32*)((char*)Ps[wid] + byteoff) = cvtpk(p[f][r], p[f][r+1]);
        }

      __builtin_amdgcn_s_setprio(1);
      #pragma unroll
      for (int kk = 0; kk < 2; kk++){
        bf16x8 pf = *(const bf16x8*)((const char*)Ps[wid] +
                      ((ql*128 + kk*64 + lg*16) ^ ((ql & 7) << 4)));
        #pragma unroll
        for (int ni = 0; ni < 4; ni++){
          int d = ni*16 + ql;
          bf16x8 vf = *(const bf16x8*)((const char*)Vt[c0] +
                        ((d*128 + kk*64 + lg*16) ^ ((d & 7) << 4)));
          oacc[ni] = mfma16(vf, pf, oacc[ni]);
        }
      }
      __builtin_amdgcn_s_setprio(0);
    }

    if (kt + 1 < NT){
      if (have2) asm volatile("s_waitcnt vmcnt(2)" ::: "memory");  // stage(t+1) done
      else       asm volatile("s_waitcnt vmcnt(0)" ::: "memory");  // final drain
      __builtin_amdgcn_s_barrier();
    }
    int tmp = c0; c0 = c1; c1 = c2; c2 = tmp;
  }
  #undef STAGE_A

  lsum += __shfl_xor(lsum, 16);
  lsum += __shfl_xor(lsum, 32);
  const float rl = 1.0f / lsum;
  #pragma unroll
  for (int ni = 0; ni < 4; ni++)
    #pragma unroll
    for (int r = 0; r < 4; r += 2){
      int d = ni*16 + lg*4 + r;
      int byteoff = (ql*128 + d*2) ^ ((ql & 7) << 4);
      *(u32*)((char*)Ps[wid] + byteoff) = cvtpk(oacc[ni][r]*rl, oacc[ni][r+1]*rl);
    }
  #pragma unroll
  for (int pass = 0; pass < 2; pass++){
    int qr = pass*8 + (lane >> 3);
    int d0 = (lane & 7)*8;
    bf16x8 row = *(const bf16x8*)((const char*)Ps[wid] + ((qr*128 + d0*2) ^ ((qr & 7) << 4)));
    *(bf16x8*)(AO + base + (size_t)(qw + qr)*DM + d0) = row;
  }
}

// ---------------- launch ----------------
extern "C" void kernel_launch(void* const* d_in, const int* in_sizes, int n_in,
                              void* d_out, int out_size, void* d_ws, size_t ws_size,
                              hipStream_t stream){
  const float* x   = (const float*)d_in[0];
  const float* Wq  = (const float*)d_in[1];
  const float* Wk  = (const float*)d_in[2];
  const float* Wv  = (const float*)d_in[3];
  const float* Wo  = (const float*)d_in[4];
  const int*   pos = (const int*)d_in[5];
  float* out = (float*)d_out;

  const size_t NEED = ((size_t)41 << 20);   // 40 MiB buffers + 512 KiB trig table
  if (ws_size < NEED){
    hipMemsetAsync(d_out, 0x7f, (size_t)out_size * sizeof(float), stream);
    return;
  }

  char* ws = (char*)d_ws;
  u16* xb   = (u16*)(ws);
  u16* Wb   = (u16*)(ws + ((size_t)8  << 20));
  u16* Qb   = (u16*)(ws + ((size_t)16 << 20));
  u16* Kb   = (u16*)(ws + ((size_t)24 << 20));
  u16* Vt   = (u16*)(ws + ((size_t)32 << 20));   // V^T [b][h*64+d][s]
  float* tab = (float*)(ws + ((size_t)40 << 20));
  u16* AO = xb;

  k_cast<<<8448, 256, 0, stream>>>(x, Wq, Wk, Wv, Wo, xb, Wb, tab);
  k_gemm_qkv<<<dim3(8, 32, 3), 256, 0, stream>>>(xb, Wb, Qb, Kb, Vt, pos, tab);
  k_attn<<<dim3(16, 16, 2), 512, 0, stream>>>(Qb, Kb, Vt, AO);
  k_gemm_out<<<dim3(8, 32), 256, 0, stream>>>(AO, Wb + ((size_t)3 << 20), out);
}